// Round 1
// baseline (348.896 us; speedup 1.0000x reference)
//
#include <hip/hip_runtime.h>
#include <hip/hip_bf16.h>

// Table-batched EmbeddingBag(sum):
//   values:  [F, N]   int32
//   offsets: [F, B+1] int32 (CSR bag boundaries)
//   tables:  [F, V, D] float32
//   out:     [B, F, D] float32
//
// One 64-lane wave per (f, b) bag; lane owns float2 slice of D=128.

constexpr int F_ = 26;
constexpr int V_ = 100000;
constexpr int D_ = 128;
constexpr int B_ = 4096;

__global__ __launch_bounds__(256) void embbag_kernel(
    const int* __restrict__ values,
    const int* __restrict__ offsets,
    const float* __restrict__ tables,
    float* __restrict__ out,
    int n_per_table)
{
    // 4 waves per block, one bag per wave. Bag id is f-major so consecutive
    // blocks reuse the same table (keeps the 51 MB table hot in L3).
    const int bag  = blockIdx.x * 4 + (threadIdx.x >> 6);
    if (bag >= F_ * B_) return;
    const int lane = threadIdx.x & 63;

    const int f = bag / B_;
    const int b = bag - f * B_;

    const int* offs = offsets + f * (B_ + 1);
    const int start = offs[b];
    const int end   = offs[b + 1];

    const int*    vals = values + (size_t)f * n_per_table;
    const float2* tab  = (const float2*)(tables + (size_t)f * V_ * D_);

    float2 a0 = {0.f, 0.f};
    float2 a1 = {0.f, 0.f};

    int p = start;
    // 2-deep unroll: two independent index loads + two row loads in flight.
    for (; p + 1 < end; p += 2) {
        const int r0 = vals[p];
        const int r1 = vals[p + 1];
        const float2 v0 = tab[(size_t)r0 * (D_ / 2) + lane];
        const float2 v1 = tab[(size_t)r1 * (D_ / 2) + lane];
        a0.x += v0.x; a0.y += v0.y;
        a1.x += v1.x; a1.y += v1.y;
    }
    if (p < end) {
        const int r0 = vals[p];
        const float2 v0 = tab[(size_t)r0 * (D_ / 2) + lane];
        a0.x += v0.x; a0.y += v0.y;
    }

    float2* o = (float2*)(out + ((size_t)b * F_ + f) * D_);
    o[lane] = make_float2(a0.x + a1.x, a0.y + a1.y);
}

extern "C" void kernel_launch(void* const* d_in, const int* in_sizes, int n_in,
                              void* d_out, int out_size, void* d_ws, size_t ws_size,
                              hipStream_t stream) {
    const int*   values  = (const int*)d_in[0];
    const int*   offsets = (const int*)d_in[1];
    const float* tables  = (const float*)d_in[2];
    float*       out     = (float*)d_out;

    const int n_per_table = in_sizes[0] / F_;   // N = B*L = 81920

    const int total_bags = F_ * B_;             // 106496
    const int bags_per_block = 4;               // 256 threads / 64
    const int grid = (total_bags + bags_per_block - 1) / bags_per_block;

    embbag_kernel<<<grid, 256, 0, stream>>>(values, offsets, tables, out, n_per_table);
}

// Round 3
// 181.651 us; speedup vs baseline: 1.9207x; 1.9207x over previous
//
#include <hip/hip_runtime.h>
#include <hip/hip_bf16.h>

// Table-batched EmbeddingBag(sum):
//   values:  [F, N]   int32
//   offsets: [F, B+1] int32 (CSR bag boundaries)
//   tables:  [F, V, D] float32
//   out:     [B, F, D] float32
//
// One 64-lane wave per (f, b) bag.
// - Bag indices preloaded 64-at-a-time in ONE coalesced load, broadcast via shfl.
// - 32 lanes per row (float4 = 16 B/lane), 2 rows per step, unrolled x4
//   => 8 independent 512 B row loads in flight per wave.

constexpr int F_ = 26;
constexpr int V_ = 100000;
constexpr int D_ = 128;
constexpr int B_ = 4096;

typedef float nfloat4 __attribute__((ext_vector_type(4)));  // native vec for nontemporal store

__global__ __launch_bounds__(256) void embbag_kernel(
    const int* __restrict__ values,
    const int* __restrict__ offsets,
    const float* __restrict__ tables,
    float* __restrict__ out,
    int n_per_table)
{
    const int bag  = blockIdx.x * 4 + (threadIdx.x >> 6);
    if (bag >= F_ * B_) return;
    const int lane = threadIdx.x & 63;
    const int half = lane >> 5;      // 0: even rows, 1: odd rows
    const int l5   = lane & 31;      // float4 slot within row (32*16B = 512B)

    const int f = bag / B_;
    const int b = bag - f * B_;

    const int* offs  = offsets + f * (B_ + 1);
    const int  start = offs[b];
    const int  end   = offs[b + 1];

    const int*    vals = values + (size_t)f * n_per_table;
    const float4* tab  = (const float4*)(tables + (size_t)f * V_ * D_);

    float4 acc = {0.f, 0.f, 0.f, 0.f};

    for (int chunk = start; chunk < end; chunk += 64) {
        const int clen = min(64, end - chunk);
        // One coalesced 64-lane index load for up to 64 bag entries.
        const int pos = chunk + lane;
        const int idx = vals[pos < end ? pos : end - 1];

        int j = 0;
        // 8 rows per step: each half-wave owns 4 alternating rows.
        for (; j + 8 <= clen; j += 8) {
            int   r[4];
            float4 v[4];
#pragma unroll
            for (int u = 0; u < 4; ++u)
                r[u] = __shfl(idx, j + 2 * u + half);
#pragma unroll
            for (int u = 0; u < 4; ++u)
                v[u] = tab[(size_t)r[u] * 32 + l5];
#pragma unroll
            for (int u = 0; u < 4; ++u) {
                acc.x += v[u].x; acc.y += v[u].y;
                acc.z += v[u].z; acc.w += v[u].w;
            }
        }
        // 2 rows per step remainder.
        for (; j + 2 <= clen; j += 2) {
            const int   r = __shfl(idx, j + half);
            const float4 v = tab[(size_t)r * 32 + l5];
            acc.x += v.x; acc.y += v.y; acc.z += v.z; acc.w += v.w;
        }
        // Odd leftover row: both halves load (same addresses), half 0 adds.
        if (j < clen) {
            const int   r = __shfl(idx, j);
            const float4 v = tab[(size_t)r * 32 + l5];
            if (half == 0) {
                acc.x += v.x; acc.y += v.y; acc.z += v.z; acc.w += v.w;
            }
        }
    }

    // Fold odd-row half into even-row half.
    float4 oth;
    oth.x = __shfl_xor(acc.x, 32);
    oth.y = __shfl_xor(acc.y, 32);
    oth.z = __shfl_xor(acc.z, 32);
    oth.w = __shfl_xor(acc.w, 32);
    acc.x += oth.x; acc.y += oth.y; acc.z += oth.z; acc.w += oth.w;

    if (half == 0) {
        nfloat4* o = (nfloat4*)(out + ((size_t)b * F_ + f) * D_);
        nfloat4 st; st.x = acc.x; st.y = acc.y; st.z = acc.z; st.w = acc.w;
        __builtin_nontemporal_store(st, o + l5);
    }
}

extern "C" void kernel_launch(void* const* d_in, const int* in_sizes, int n_in,
                              void* d_out, int out_size, void* d_ws, size_t ws_size,
                              hipStream_t stream) {
    const int*   values  = (const int*)d_in[0];
    const int*   offsets = (const int*)d_in[1];
    const float* tables  = (const float*)d_in[2];
    float*       out     = (float*)d_out;

    const int n_per_table = in_sizes[0] / F_;   // N = B*L = 81920

    const int total_bags = F_ * B_;             // 106496
    const int bags_per_block = 4;               // 256 threads / 64
    const int grid = (total_bags + bags_per_block - 1) / bags_per_block;

    embbag_kernel<<<grid, 256, 0, stream>>>(values, offsets, tables, out, n_per_table);
}